// Round 2
// 209.830 us; speedup vs baseline: 1.0802x; 1.0802x over previous
//
#include <hip/hip_runtime.h>
#include <math.h>

typedef __attribute__((ext_vector_type(8))) short short8;   // 8 bf16 (4 VGPRs)
typedef __attribute__((ext_vector_type(4))) float f32x4;    // MFMA accumulator

constexpr int kD  = 2048;
constexpr int kE  = 64;
constexpr int kM  = 32;          // tokens per block -> 512 blocks -> 2/CU
constexpr int kBK = 128;         // K per staging iteration
constexpr int kIt = kD / kBK;    // 16
// A-limb LDS, fragment order per 16-token tile: addr = (16o+r)*48 + o*16 + j*2
constexpr int kTS  = 3136;       // per-tile stride bytes (o-padded, bank-clean)
constexpr int kCS2 = 2 * kTS;    // chunk stride: 2 token-tiles
constexpr int kBuf = 4 * kCS2;   // 25088 B per staging buffer (4 chunks)

// p limbs pre-converted to MFMA B-fragment order:
// g_B[plane][e0=e>>4][gc=k>>5][L=16*((k>>3)&3)+(e&15)][j=k&7]   (ushorts)
constexpr int kPlaneU = 4 * 64 * 512;   // 131072 ushorts per plane
__device__ unsigned short g_B[3 * kPlaneU];   // 786 KB

// 3-limb truncated bf16 split: v = h + m + l + O(2^-24 |v|)
__device__ __forceinline__ void split3(float v, unsigned& h, unsigned& m, unsigned& l) {
  unsigned u = __float_as_uint(v);
  h = u & 0xFFFF0000u;
  float r1 = v - __uint_as_float(h);
  m = __float_as_uint(r1) & 0xFFFF0000u;
  float r2 = r1 - __uint_as_float(m);
  l = __float_as_uint(r2);
}

// pack limbs of two consecutive elements into one dword per plane
__device__ __forceinline__ void pack2(float e0, float e1,
                                      unsigned& dh, unsigned& dm, unsigned& dl) {
  unsigned h0, m0, l0, h1, m1, l1;
  split3(e0, h0, m0, l0);
  split3(e1, h1, m1, l1);
  dh = (h0 >> 16) | h1;
  dm = (m0 >> 16) | m1;
  dl = (l0 >> 16) | (l1 & 0xFFFF0000u);
}

// ---------------------------------------------------------------------------
// Prep: S_e, inv_norm_e into ws; p 3-limb bf16 into g_B in B-fragment order.
// ---------------------------------------------------------------------------
__global__ __launch_bounds__(256) void proto_prep(const float* __restrict__ p,
                                                  float* __restrict__ ws) {
  const int e = blockIdx.x, t = threadIdx.x;
  const float* row = p + (size_t)e * kD;
  float4 v0 = *(const float4*)(row + 8 * t);
  float4 v1 = *(const float4*)(row + 8 * t + 4);

  unsigned dh[4], dm[4], dl[4];
  pack2(v0.x, v0.y, dh[0], dm[0], dl[0]);
  pack2(v0.z, v0.w, dh[1], dm[1], dl[1]);
  pack2(v1.x, v1.y, dh[2], dm[2], dl[2]);
  pack2(v1.z, v1.w, dh[3], dm[3], dl[3]);
  const int gc = t >> 2, o = t & 3;
  size_t base = (size_t)((e >> 4) * 64 + gc) * 512 + (16 * o + (e & 15)) * 8;
  *(uint4*)&g_B[base]               = make_uint4(dh[0], dh[1], dh[2], dh[3]);
  *(uint4*)&g_B[kPlaneU + base]     = make_uint4(dm[0], dm[1], dm[2], dm[3]);
  *(uint4*)&g_B[2 * kPlaneU + base] = make_uint4(dl[0], dl[1], dl[2], dl[3]);

  float s = (v0.x + v0.y) + (v0.z + v0.w) + (v1.x + v1.y) + (v1.z + v1.w);
  float q = v0.x*v0.x + v0.y*v0.y + v0.z*v0.z + v0.w*v0.w
          + v1.x*v1.x + v1.y*v1.y + v1.z*v1.z + v1.w*v1.w;
  #pragma unroll
  for (int off = 32; off >= 1; off >>= 1) {
    s += __shfl_xor(s, off, 64);
    q += __shfl_xor(q, off, 64);
  }
  __shared__ float as[4], aq[4];
  if ((t & 63) == 0) { as[t >> 6] = s; aq[t >> 6] = q; }
  __syncthreads();
  if (t == 0) {
    float S = (as[0] + as[1]) + (as[2] + as[3]);
    float Q = (aq[0] + aq[1]) + (aq[2] + aq[3]);
    ws[e]      = S;
    ws[kE + e] = 1.f / fmaxf(sqrtf(Q), 1e-8f);
  }
}

// ---------------------------------------------------------------------------
// Main: 32 tokens/block, 4 waves n-split (16 experts each), 2 M-tiles/wave so
// every B fragment feeds 2 accumulators (halves B L1/L2 traffic). Double-
// buffered LDS staging (1 barrier/iter); B +1-step, A +1-step, x +1-iter
// register prefetch. Numerics identical to the 225 us version.
// ---------------------------------------------------------------------------
__global__ __launch_bounds__(256, 2) void router_main(
    const float* __restrict__ x, const float* __restrict__ ws,
    float* __restrict__ out_w, float* __restrict__ out_i) {
  __shared__ __align__(16) unsigned char sA[2 * kBuf];  // 50176 B
  __shared__ float sLogit[kM * 68];                     //  8704 B
  __shared__ float sStats[kM][2];                       //   256 B

  const int t    = threadIdx.x;
  const int w    = t >> 6;          // wave: experts [16w, 16w+16)
  const int L    = t & 63;
  const int ln15 = L & 15;
  const int q    = L >> 4;
  const int tok0 = blockIdx.x * kM;
  const float* xg = x + (size_t)tok0 * kD;

  // staging geometry, fixed per thread: token base mB (+8 per slice), k-col kc
  const int mB = t >> 5;            // 0..7
  const int kc = (t & 31) * 4;      // 0..124
  const int c_s = kc >> 5;
  const int o_s = (kc >> 3) & 3;
  const int j_s = kc & 7;
  const int wcol = (16 * o_s) * 48 + o_s * 16 + j_s * 2;

  f32x4 acc0 = (f32x4){0.f, 0.f, 0.f, 0.f};
  f32x4 acc1 = (f32x4){0.f, 0.f, 0.f, 0.f};
  float sx[4]  = {0.f, 0.f, 0.f, 0.f};
  float sxx[4] = {0.f, 0.f, 0.f, 0.f};

  auto stage = [&](const float4 v, float& sxr, float& sxxr, int m, unsigned char* wb) {
    unsigned dh0, dm0, dl0, dh1, dm1, dl1;
    pack2(v.x, v.y, dh0, dm0, dl0);
    pack2(v.z, v.w, dh1, dm1, dl1);
    sxr += (v.x + v.y) + (v.z + v.w);
    sxxr = fmaf(v.x, v.x, fmaf(v.y, v.y, fmaf(v.z, v.z, fmaf(v.w, v.w, sxxr))));
    unsigned char* dst = wb + c_s * kCS2 + (m >> 4) * kTS + (m & 15) * 48 + wcol;
    *(uint2*)(dst)      = make_uint2(dh0, dh1);   // plane h
    *(uint2*)(dst + 16) = make_uint2(dm0, dm1);   // plane m
    *(uint2*)(dst + 32) = make_uint2(dl0, dl1);   // plane l
  };

  // ---- prologue: stage chunk 0 into buf0, prefetch chunk 1, preload B(gc=0)
  float4 pfA[4], pfB[4];
  #pragma unroll
  for (int jj = 0; jj < 4; ++jj)
    pfA[jj] = *(const float4*)(xg + (size_t)(mB + 8 * jj) * kD + kc);
  #pragma unroll
  for (int jj = 0; jj < 4; ++jj)
    stage(pfA[jj], sx[jj], sxx[jj], mB + 8 * jj, sA);
  #pragma unroll
  for (int jj = 0; jj < 4; ++jj)
    pfA[jj] = *(const float4*)(xg + (size_t)(mB + 8 * jj) * kD + kBK + kc);

  short8 Bh, Bm, Bl;
  {
    const size_t bo = (size_t)(w * 64) * 512 + L * 8;
    Bh = *(const short8*)&g_B[bo];
    Bm = *(const short8*)&g_B[kPlaneU + bo];
    Bl = *(const short8*)&g_B[2 * kPlaneU + bo];
  }
  __syncthreads();

  const int aoff = L * 48 + (L >> 4) * 16;

  for (int it = 0; it < kIt; ++it) {
    unsigned char* rbase = sA + (it & 1) * kBuf;
    unsigned char* wbase = sA + ((it & 1) ^ 1) * kBuf;

    if (it + 2 < kIt) {
      #pragma unroll
      for (int jj = 0; jj < 4; ++jj)
        pfB[jj] = *(const float4*)(xg + (size_t)(mB + 8 * jj) * kD + (it + 2) * kBK + kc);
    }

    // A fragments for c = 0 (both tiles, 3 planes)
    const unsigned char* ra = rbase + aoff;
    short8 Ah0 = *(const short8*)(ra);
    short8 Am0 = *(const short8*)(ra + 16);
    short8 Al0 = *(const short8*)(ra + 32);
    short8 Ah1 = *(const short8*)(ra + kTS);
    short8 Am1 = *(const short8*)(ra + kTS + 16);
    short8 Al1 = *(const short8*)(ra + kTS + 32);

    const bool do_stage = (it + 1 < kIt);

    #pragma unroll
    for (int c = 0; c < 4; ++c) {
      // prefetch next B (wraps harmlessly at the very end)
      const int ngc = (it * 4 + c + 1) & 63;
      const size_t nbo = (size_t)(w * 64 + ngc) * 512 + L * 8;
      short8 nBh = *(const short8*)&g_B[nbo];
      short8 nBm = *(const short8*)&g_B[kPlaneU + nbo];
      short8 nBl = *(const short8*)&g_B[2 * kPlaneU + nbo];

      // prefetch next A (defensively initialized; copies are guarded)
      short8 nAh0 = Ah0, nAm0 = Am0, nAl0 = Al0;
      short8 nAh1 = Ah1, nAm1 = Am1, nAl1 = Al1;
      if (c < 3) {
        const unsigned char* rn = rbase + (c + 1) * kCS2 + aoff;
        nAh0 = *(const short8*)(rn);
        nAm0 = *(const short8*)(rn + 16);
        nAl0 = *(const short8*)(rn + 32);
        nAh1 = *(const short8*)(rn + kTS);
        nAm1 = *(const short8*)(rn + kTS + 16);
        nAl1 = *(const short8*)(rn + kTS + 32);
      }

      // 6 limb products per tile: hh, hm, mh, mm, hl, lh (order preserved)
      acc0 = __builtin_amdgcn_mfma_f32_16x16x32_bf16(Ah0, Bh, acc0, 0, 0, 0);
      acc1 = __builtin_amdgcn_mfma_f32_16x16x32_bf16(Ah1, Bh, acc1, 0, 0, 0);
      acc0 = __builtin_amdgcn_mfma_f32_16x16x32_bf16(Ah0, Bm, acc0, 0, 0, 0);
      acc1 = __builtin_amdgcn_mfma_f32_16x16x32_bf16(Ah1, Bm, acc1, 0, 0, 0);
      acc0 = __builtin_amdgcn_mfma_f32_16x16x32_bf16(Am0, Bh, acc0, 0, 0, 0);
      acc1 = __builtin_amdgcn_mfma_f32_16x16x32_bf16(Am1, Bh, acc1, 0, 0, 0);
      acc0 = __builtin_amdgcn_mfma_f32_16x16x32_bf16(Am0, Bm, acc0, 0, 0, 0);
      acc1 = __builtin_amdgcn_mfma_f32_16x16x32_bf16(Am1, Bm, acc1, 0, 0, 0);
      acc0 = __builtin_amdgcn_mfma_f32_16x16x32_bf16(Ah0, Bl, acc0, 0, 0, 0);
      acc1 = __builtin_amdgcn_mfma_f32_16x16x32_bf16(Ah1, Bl, acc1, 0, 0, 0);
      acc0 = __builtin_amdgcn_mfma_f32_16x16x32_bf16(Al0, Bh, acc0, 0, 0, 0);
      acc1 = __builtin_amdgcn_mfma_f32_16x16x32_bf16(Al1, Bh, acc1, 0, 0, 0);

      // stage slice c of next iteration's x-chunk into the other buffer
      if (do_stage)
        stage(pfA[c], sx[c], sxx[c], mB + 8 * c, wbase);

      Bh = nBh; Bm = nBm; Bl = nBl;
      Ah0 = nAh0; Am0 = nAm0; Al0 = nAl0;
      Ah1 = nAh1; Am1 = nAm1; Al1 = nAl1;
    }

    __syncthreads();
    if (it + 2 < kIt) {
      #pragma unroll
      for (int jj = 0; jj < 4; ++jj) pfA[jj] = pfB[jj];
    }
  }

  // LN stats: reduce within each 32-lane (same-token-row) group
  #pragma unroll
  for (int jj = 0; jj < 4; ++jj) {
    float a = sx[jj], b = sxx[jj];
    #pragma unroll
    for (int off = 16; off >= 1; off >>= 1) {
      a += __shfl_xor(a, off, 64);
      b += __shfl_xor(b, off, 64);
    }
    if ((L & 31) == 0) {
      int m = mB + 8 * jj;      // L=0 -> 2w ; L=32 -> 2w+1
      sStats[m][0] = a;
      sStats[m][1] = b;
    }
  }

  // raw dots -> LDS  (row = token, col = expert)
  #pragma unroll
  for (int i = 0; i < 4; ++i) {
    sLogit[(q * 4 + i) * 68 + w * 16 + ln15]      = acc0[i];
    sLogit[(16 + q * 4 + i) * 68 + w * 16 + ln15] = acc1[i];
  }
  __syncthreads();

  // epilogue: wave w -> tokens [8w, 8w+8), lane = expert
  const float Se  = ws[L];
  const float inv = ws[kE + L];
  #pragma unroll
  for (int tl = 0; tl < 8; ++tl) {
    int tk = w * 8 + tl;
    float mu   = sStats[tk][0] * (1.f / kD);
    float var  = sStats[tk][1] * (1.f / kD) - mu * mu;
    float rstd = rsqrtf(var + 1e-5f);
    float logit = (sLogit[tk * 68 + L] - mu * Se) * rstd * inv * 0.125f;

    float v1 = logit; int i1 = L;
    #pragma unroll
    for (int off = 32; off >= 1; off >>= 1) {
      float ov = __shfl_xor(v1, off, 64);
      int   oi = __shfl_xor(i1, off, 64);
      if (ov > v1 || (ov == v1 && oi < i1)) { v1 = ov; i1 = oi; }
    }
    float ml = (L == i1) ? -3.402823466e38f : logit;
    float v2 = ml; int i2 = L;
    #pragma unroll
    for (int off = 32; off >= 1; off >>= 1) {
      float ov = __shfl_xor(v2, off, 64);
      int   oi = __shfl_xor(i2, off, 64);
      if (ov > v2 || (ov == v2 && oi < i2)) { v2 = ov; i2 = oi; }
    }
    if (L == 0) {
      int tg = tok0 + tk;
      float er = expf(v2 - v1);
      float r  = 1.f / (1.f + er);
      out_w[2 * tg]     = r;
      out_w[2 * tg + 1] = er * r;
      out_i[2 * tg]     = (float)i1;   // harness reads whole buffer as f32
      out_i[2 * tg + 1] = (float)i2;
    }
  }
}

extern "C" void kernel_launch(void* const* d_in, const int* in_sizes, int n_in,
                              void* d_out, int out_size, void* d_ws, size_t ws_size,
                              hipStream_t stream) {
  const float* x = (const float*)d_in[0];   // [4,4096,2048] fp32
  const float* p = (const float*)d_in[1];   // [64,2048] fp32
  float* ws = (float*)d_ws;                 // 128 floats
  const int T = in_sizes[0] / kD;           // 16384 tokens
  float* out_w = (float*)d_out;
  float* out_i = (float*)d_out + (size_t)T * 2;

  proto_prep<<<kE, 256, 0, stream>>>(p, ws);
  router_main<<<T / kM, 256, 0, stream>>>(x, ws, out_w, out_i);
}

// Round 3
// 206.076 us; speedup vs baseline: 1.0998x; 1.0182x over previous
//
#include <hip/hip_runtime.h>
#include <math.h>

typedef __attribute__((ext_vector_type(8))) short short8;   // 8 bf16 (4 VGPRs)
typedef __attribute__((ext_vector_type(4))) float f32x4;    // MFMA accumulator

constexpr int kD  = 2048;
constexpr int kE  = 64;
constexpr int kM  = 32;          // tokens per block -> 512 blocks -> 2/CU
constexpr int kBK = 128;         // K per staging iteration
constexpr int kIt = kD / kBK;    // 16
// A-limb LDS, fragment order per 16-token tile: addr = (16o+r)*48 + o*16 + j*2
constexpr int kTS  = 3136;       // per-tile stride bytes (o-padded, bank-clean)
constexpr int kCS2 = 2 * kTS;    // chunk stride: 2 token-tiles
constexpr int kBuf = 4 * kCS2;   // 25088 B per staging buffer (4 chunks)

// p limbs pre-converted to MFMA B-fragment order:
// g_B[plane][e0=e>>4][gc=k>>5][L=16*((k>>3)&3)+(e&15)][j=k&7]   (ushorts)
constexpr int kPlaneU = 4 * 64 * 512;   // 131072 ushorts per plane
__device__ unsigned short g_B[3 * kPlaneU];   // 786 KB

// 3-limb truncated bf16 split: v = h + m + l + O(2^-24 |v|)
__device__ __forceinline__ void split3(float v, unsigned& h, unsigned& m, unsigned& l) {
  unsigned u = __float_as_uint(v);
  h = u & 0xFFFF0000u;
  float r1 = v - __uint_as_float(h);
  m = __float_as_uint(r1) & 0xFFFF0000u;
  float r2 = r1 - __uint_as_float(m);
  l = __float_as_uint(r2);
}

// pack limbs of two consecutive elements into one dword per plane
__device__ __forceinline__ void pack2(float e0, float e1,
                                      unsigned& dh, unsigned& dm, unsigned& dl) {
  unsigned h0, m0, l0, h1, m1, l1;
  split3(e0, h0, m0, l0);
  split3(e1, h1, m1, l1);
  dh = (h0 >> 16) | h1;
  dm = (m0 >> 16) | m1;
  dl = (l0 >> 16) | (l1 & 0xFFFF0000u);
}

// ---------------------------------------------------------------------------
// Prep: S_e, inv_norm_e into ws; p 3-limb bf16 into g_B in B-fragment order.
// ---------------------------------------------------------------------------
__global__ __launch_bounds__(256) void proto_prep(const float* __restrict__ p,
                                                  float* __restrict__ ws) {
  const int e = blockIdx.x, t = threadIdx.x;
  const float* row = p + (size_t)e * kD;
  float4 v0 = *(const float4*)(row + 8 * t);
  float4 v1 = *(const float4*)(row + 8 * t + 4);

  unsigned dh[4], dm[4], dl[4];
  pack2(v0.x, v0.y, dh[0], dm[0], dl[0]);
  pack2(v0.z, v0.w, dh[1], dm[1], dl[1]);
  pack2(v1.x, v1.y, dh[2], dm[2], dl[2]);
  pack2(v1.z, v1.w, dh[3], dm[3], dl[3]);
  const int gc = t >> 2, o = t & 3;
  size_t base = (size_t)((e >> 4) * 64 + gc) * 512 + (16 * o + (e & 15)) * 8;
  *(uint4*)&g_B[base]               = make_uint4(dh[0], dh[1], dh[2], dh[3]);
  *(uint4*)&g_B[kPlaneU + base]     = make_uint4(dm[0], dm[1], dm[2], dm[3]);
  *(uint4*)&g_B[2 * kPlaneU + base] = make_uint4(dl[0], dl[1], dl[2], dl[3]);

  float s = (v0.x + v0.y) + (v0.z + v0.w) + (v1.x + v1.y) + (v1.z + v1.w);
  float q = v0.x*v0.x + v0.y*v0.y + v0.z*v0.z + v0.w*v0.w
          + v1.x*v1.x + v1.y*v1.y + v1.z*v1.z + v1.w*v1.w;
  #pragma unroll
  for (int off = 32; off >= 1; off >>= 1) {
    s += __shfl_xor(s, off, 64);
    q += __shfl_xor(q, off, 64);
  }
  __shared__ float as[4], aq[4];
  if ((t & 63) == 0) { as[t >> 6] = s; aq[t >> 6] = q; }
  __syncthreads();
  if (t == 0) {
    float S = (as[0] + as[1]) + (as[2] + as[3]);
    float Q = (aq[0] + aq[1]) + (aq[2] + aq[3]);
    ws[e]      = S;
    ws[kE + e] = 1.f / fmaxf(sqrtf(Q), 1e-8f);
  }
}

// ---------------------------------------------------------------------------
// Main: 32 tokens/block, 4 waves n-split (16 experts each), 2 M-tiles/wave.
// B register pipeline deepened to distance 2 (covers ~200cy L2-hit latency);
// staging writes issued before the MFMA cluster; setprio around MFMAs.
// Numerics identical to the 225 us version.
// ---------------------------------------------------------------------------
__global__ __launch_bounds__(256, 2) void router_main(
    const float* __restrict__ x, const float* __restrict__ ws,
    float* __restrict__ out_w, float* __restrict__ out_i) {
  __shared__ __align__(16) unsigned char sA[2 * kBuf];  // 50176 B
  __shared__ float sLogit[kM * 68];                     //  8704 B
  __shared__ float sStats[kM][2];                       //   256 B

  const int t    = threadIdx.x;
  const int w    = t >> 6;          // wave: experts [16w, 16w+16)
  const int L    = t & 63;
  const int ln15 = L & 15;
  const int q    = L >> 4;
  const int tok0 = blockIdx.x * kM;
  const float* xg = x + (size_t)tok0 * kD;

  // staging geometry, fixed per thread: token base mB (+8 per slice), k-col kc
  const int mB = t >> 5;            // 0..7
  const int kc = (t & 31) * 4;      // 0..124
  const int c_s = kc >> 5;
  const int o_s = (kc >> 3) & 3;
  const int j_s = kc & 7;
  const int wcol = (16 * o_s) * 48 + o_s * 16 + j_s * 2;

  f32x4 acc0 = (f32x4){0.f, 0.f, 0.f, 0.f};
  f32x4 acc1 = (f32x4){0.f, 0.f, 0.f, 0.f};
  float sx[4]  = {0.f, 0.f, 0.f, 0.f};
  float sxx[4] = {0.f, 0.f, 0.f, 0.f};

  auto stage = [&](const float4 v, float& sxr, float& sxxr, int m, unsigned char* wb) {
    unsigned dh0, dm0, dl0, dh1, dm1, dl1;
    pack2(v.x, v.y, dh0, dm0, dl0);
    pack2(v.z, v.w, dh1, dm1, dl1);
    sxr += (v.x + v.y) + (v.z + v.w);
    sxxr = fmaf(v.x, v.x, fmaf(v.y, v.y, fmaf(v.z, v.z, fmaf(v.w, v.w, sxxr))));
    unsigned char* dst = wb + c_s * kCS2 + (m >> 4) * kTS + (m & 15) * 48 + wcol;
    *(uint2*)(dst)      = make_uint2(dh0, dh1);   // plane h
    *(uint2*)(dst + 16) = make_uint2(dm0, dm1);   // plane m
    *(uint2*)(dst + 32) = make_uint2(dl0, dl1);   // plane l
  };

  // ---- prologue: stage chunk 0 into buf0, prefetch chunk 1, preload B(0),B(1)
  float4 pfA[4], pfB[4];
  #pragma unroll
  for (int jj = 0; jj < 4; ++jj)
    pfA[jj] = *(const float4*)(xg + (size_t)(mB + 8 * jj) * kD + kc);
  #pragma unroll
  for (int jj = 0; jj < 4; ++jj)
    stage(pfA[jj], sx[jj], sxx[jj], mB + 8 * jj, sA);
  #pragma unroll
  for (int jj = 0; jj < 4; ++jj)
    pfA[jj] = *(const float4*)(xg + (size_t)(mB + 8 * jj) * kD + kBK + kc);

  short8 Bch, Bcm, Bcl, Bnh, Bnm, Bnl;
  {
    const size_t bo0 = (size_t)(w * 64 + 0) * 512 + L * 8;
    Bch = *(const short8*)&g_B[bo0];
    Bcm = *(const short8*)&g_B[kPlaneU + bo0];
    Bcl = *(const short8*)&g_B[2 * kPlaneU + bo0];
    const size_t bo1 = (size_t)(w * 64 + 1) * 512 + L * 8;
    Bnh = *(const short8*)&g_B[bo1];
    Bnm = *(const short8*)&g_B[kPlaneU + bo1];
    Bnl = *(const short8*)&g_B[2 * kPlaneU + bo1];
  }
  __syncthreads();

  const int aoff = L * 48 + (L >> 4) * 16;

  for (int it = 0; it < kIt; ++it) {
    unsigned char* rbase = sA + (it & 1) * kBuf;
    unsigned char* wbase = sA + ((it & 1) ^ 1) * kBuf;

    if (it + 2 < kIt) {
      #pragma unroll
      for (int jj = 0; jj < 4; ++jj)
        pfB[jj] = *(const float4*)(xg + (size_t)(mB + 8 * jj) * kD + (it + 2) * kBK + kc);
    }

    // A fragments for c = 0 (both tiles, 3 planes)
    const unsigned char* ra = rbase + aoff;
    short8 Ah0 = *(const short8*)(ra);
    short8 Am0 = *(const short8*)(ra + 16);
    short8 Al0 = *(const short8*)(ra + 32);
    short8 Ah1 = *(const short8*)(ra + kTS);
    short8 Am1 = *(const short8*)(ra + kTS + 16);
    short8 Al1 = *(const short8*)(ra + kTS + 32);

    const bool do_stage = (it + 1 < kIt);

    #pragma unroll
    for (int c = 0; c < 4; ++c) {
      // prefetch B two steps ahead (wraps harmlessly at the very end)
      const int fgc = (it * 4 + c + 2) & 63;
      const size_t fbo = (size_t)(w * 64 + fgc) * 512 + L * 8;
      short8 fBh = *(const short8*)&g_B[fbo];
      short8 fBm = *(const short8*)&g_B[kPlaneU + fbo];
      short8 fBl = *(const short8*)&g_B[2 * kPlaneU + fbo];

      // prefetch next A (defensively initialized; copies are guarded)
      short8 nAh0 = Ah0, nAm0 = Am0, nAl0 = Al0;
      short8 nAh1 = Ah1, nAm1 = Am1, nAl1 = Al1;
      if (c < 3) {
        const unsigned char* rn = rbase + (c + 1) * kCS2 + aoff;
        nAh0 = *(const short8*)(rn);
        nAm0 = *(const short8*)(rn + 16);
        nAl0 = *(const short8*)(rn + 32);
        nAh1 = *(const short8*)(rn + kTS);
        nAm1 = *(const short8*)(rn + kTS + 16);
        nAl1 = *(const short8*)(rn + kTS + 32);
      }

      // stage slice c of next iteration's x-chunk BEFORE the MFMA cluster so
      // the ds_writes drain under MFMA issue
      if (do_stage)
        stage(pfA[c], sx[c], sxx[c], mB + 8 * c, wbase);

      // 6 limb products per tile: hh, hm, mh, mm, hl, lh (order preserved)
      __builtin_amdgcn_s_setprio(1);
      acc0 = __builtin_amdgcn_mfma_f32_16x16x32_bf16(Ah0, Bch, acc0, 0, 0, 0);
      acc1 = __builtin_amdgcn_mfma_f32_16x16x32_bf16(Ah1, Bch, acc1, 0, 0, 0);
      acc0 = __builtin_amdgcn_mfma_f32_16x16x32_bf16(Ah0, Bcm, acc0, 0, 0, 0);
      acc1 = __builtin_amdgcn_mfma_f32_16x16x32_bf16(Ah1, Bcm, acc1, 0, 0, 0);
      acc0 = __builtin_amdgcn_mfma_f32_16x16x32_bf16(Am0, Bch, acc0, 0, 0, 0);
      acc1 = __builtin_amdgcn_mfma_f32_16x16x32_bf16(Am1, Bch, acc1, 0, 0, 0);
      acc0 = __builtin_amdgcn_mfma_f32_16x16x32_bf16(Am0, Bcm, acc0, 0, 0, 0);
      acc1 = __builtin_amdgcn_mfma_f32_16x16x32_bf16(Am1, Bcm, acc1, 0, 0, 0);
      acc0 = __builtin_amdgcn_mfma_f32_16x16x32_bf16(Ah0, Bcl, acc0, 0, 0, 0);
      acc1 = __builtin_amdgcn_mfma_f32_16x16x32_bf16(Ah1, Bcl, acc1, 0, 0, 0);
      acc0 = __builtin_amdgcn_mfma_f32_16x16x32_bf16(Al0, Bch, acc0, 0, 0, 0);
      acc1 = __builtin_amdgcn_mfma_f32_16x16x32_bf16(Al1, Bch, acc1, 0, 0, 0);
      __builtin_amdgcn_s_setprio(0);

      // rotate pipelines
      Bch = Bnh; Bcm = Bnm; Bcl = Bnl;
      Bnh = fBh; Bnm = fBm; Bnl = fBl;
      Ah0 = nAh0; Am0 = nAm0; Al0 = nAl0;
      Ah1 = nAh1; Am1 = nAm1; Al1 = nAl1;
    }

    __syncthreads();
    if (it + 2 < kIt) {
      #pragma unroll
      for (int jj = 0; jj < 4; ++jj) pfA[jj] = pfB[jj];
    }
  }

  // LN stats: reduce within each 32-lane (same-token-row) group
  #pragma unroll
  for (int jj = 0; jj < 4; ++jj) {
    float a = sx[jj], b = sxx[jj];
    #pragma unroll
    for (int off = 16; off >= 1; off >>= 1) {
      a += __shfl_xor(a, off, 64);
      b += __shfl_xor(b, off, 64);
    }
    if ((L & 31) == 0) {
      int m = mB + 8 * jj;
      sStats[m][0] = a;
      sStats[m][1] = b;
    }
  }

  // raw dots -> LDS  (row = token, col = expert)
  #pragma unroll
  for (int i = 0; i < 4; ++i) {
    sLogit[(q * 4 + i) * 68 + w * 16 + ln15]      = acc0[i];
    sLogit[(16 + q * 4 + i) * 68 + w * 16 + ln15] = acc1[i];
  }
  __syncthreads();

  // epilogue: wave w -> tokens [8w, 8w+8), lane = expert
  const float Se  = ws[L];
  const float inv = ws[kE + L];
  #pragma unroll
  for (int tl = 0; tl < 8; ++tl) {
    int tk = w * 8 + tl;
    float mu   = sStats[tk][0] * (1.f / kD);
    float var  = sStats[tk][1] * (1.f / kD) - mu * mu;
    float rstd = rsqrtf(var + 1e-5f);
    float logit = (sLogit[tk * 68 + L] - mu * Se) * rstd * inv * 0.125f;

    float v1 = logit; int i1 = L;
    #pragma unroll
    for (int off = 32; off >= 1; off >>= 1) {
      float ov = __shfl_xor(v1, off, 64);
      int   oi = __shfl_xor(i1, off, 64);
      if (ov > v1 || (ov == v1 && oi < i1)) { v1 = ov; i1 = oi; }
    }
    float ml = (L == i1) ? -3.402823466e38f : logit;
    float v2 = ml; int i2 = L;
    #pragma unroll
    for (int off = 32; off >= 1; off >>= 1) {
      float ov = __shfl_xor(v2, off, 64);
      int   oi = __shfl_xor(i2, off, 64);
      if (ov > v2 || (ov == v2 && oi < i2)) { v2 = ov; i2 = oi; }
    }
    if (L == 0) {
      int tg = tok0 + tk;
      float er = expf(v2 - v1);
      float r  = 1.f / (1.f + er);
      out_w[2 * tg]     = r;
      out_w[2 * tg + 1] = er * r;
      out_i[2 * tg]     = (float)i1;   // harness reads whole buffer as f32
      out_i[2 * tg + 1] = (float)i2;
    }
  }
}

extern "C" void kernel_launch(void* const* d_in, const int* in_sizes, int n_in,
                              void* d_out, int out_size, void* d_ws, size_t ws_size,
                              hipStream_t stream) {
  const float* x = (const float*)d_in[0];   // [4,4096,2048] fp32
  const float* p = (const float*)d_in[1];   // [64,2048] fp32
  float* ws = (float*)d_ws;                 // 128 floats
  const int T = in_sizes[0] / kD;           // 16384 tokens
  float* out_w = (float*)d_out;
  float* out_i = (float*)d_out + (size_t)T * 2;

  proto_prep<<<kE, 256, 0, stream>>>(p, ws);
  router_main<<<T / kM, 256, 0, stream>>>(x, ws, out_w, out_i);
}